// Round 6
// baseline (679.970 us; speedup 1.0000x reference)
//
#include <hip/hip_runtime.h>
#include <stdint.h>

typedef __attribute__((ext_vector_type(8))) short bf16x8;
typedef __attribute__((ext_vector_type(4))) float f32x4;

#define HW    36864   // 192*192
#define CCH   384
#define NPIX  73728   // 2 batches * HW
#define W2    147456  // 384*384

__device__ __forceinline__ unsigned short f2bf(float f) {
  unsigned u = __builtin_bit_cast(unsigned, f);
  u += 0x7FFFu + ((u >> 16) & 1u);
  return (unsigned short)(u >> 16);
}

typedef const unsigned int __attribute__((address_space(1)))* gas1_t;
typedef unsigned int __attribute__((address_space(3)))* las3_t;
__device__ __forceinline__ void gload16(const void* g, void* l) {
  __builtin_amdgcn_global_load_lds((gas1_t)g, (las3_t)l, 16, 0, 0);
}

// ---------------- prep kernels ----------------

// wt slots: 0=wq1, 1=wk2, 2=wv2, 3=wq2, 4=wk1, 5=wv1  (frame-fused order)
__global__ void k_wt(const float* __restrict__ w0, const float* __restrict__ w1,
                     const float* __restrict__ w2, const float* __restrict__ w3,
                     const float* __restrict__ w4, const float* __restrict__ w5,
                     unsigned short* __restrict__ wt) {
  int idx = blockIdx.x * 256 + threadIdx.x;   // 0..147455
  int w = blockIdx.y;                          // input index: q1,k1,v1,q2,k2,v2
  const float* W;
  switch (w) { case 0: W = w0; break; case 1: W = w1; break;
               case 2: W = w2; break; case 3: W = w3; break;
               case 4: W = w4; break; default: W = w5; break; }
  const int slotmap[6] = {0, 4, 5, 3, 1, 2};
  int slot = slotmap[w];
  int c = idx / 384, d = idx % 384;
  wt[(size_t)slot * W2 + (size_t)d * 384 + c] = f2bf(W[(size_t)c * 384 + d]);
}

__global__ void k_wf(const float* __restrict__ wo1, const float* __restrict__ pj1,
                     const float* __restrict__ wo2, const float* __restrict__ pj2,
                     unsigned short* __restrict__ wfT) {
  int idx = blockIdx.x * 256 + threadIdx.x;
  int s = blockIdx.y;
  const float* wo = s ? wo2 : wo1;
  const float* pj = s ? pj2 : pj1;
  int d = idx / 384, e = idx % 384;
  float acc = 0.f;
  for (int c = 0; c < 384; ++c) acc += pj[d * 384 + c] * wo[e * 384 + c];
  wfT[(size_t)s * W2 + (size_t)d * 384 + e] = f2bf(acc);
}

__global__ void k_bf(const float* __restrict__ bo1, const float* __restrict__ pj1,
                     const float* __restrict__ pb1, const float* __restrict__ bo2,
                     const float* __restrict__ pj2, const float* __restrict__ pb2,
                     float* __restrict__ bfused) {
  int t = threadIdx.x;  // 0..767
  int s = t / 384, d = t % 384;
  const float* bo = s ? bo2 : bo1;
  const float* pj = s ? pj2 : pj1;
  const float* pb = s ? pb2 : pb1;
  float acc = pb[d];
  for (int c = 0; c < 384; ++c) acc += pj[d * 384 + c] * bo[c];
  bfused[t] = acc;
}

// xbf[t][b][p][c] = bf16( x[b][c][t][p] )
__global__ __launch_bounds__(256) void k_tx(const float* __restrict__ x,
                                            unsigned short* __restrict__ xbf) {
  __shared__ float tile[64][65];
  int p0 = blockIdx.x * 64;
  int c0 = blockIdx.y * 64;
  int bt = blockIdx.z;  // b*2 + t
  int b = bt >> 1, t = bt & 1;
  int tid = threadIdx.x;
  int cl = tid >> 2;
  int pq = (tid & 3) * 4;
  const float* src = x + (((size_t)b * CCH + (c0 + cl)) * 2 + t) * HW + p0;
#pragma unroll
  for (int i = 0; i < 4; ++i) {
    int p_l = pq + i * 16;
    float4 v = *reinterpret_cast<const float4*>(src + p_l);
    tile[cl][p_l + 0] = v.x; tile[cl][p_l + 1] = v.y;
    tile[cl][p_l + 2] = v.z; tile[cl][p_l + 3] = v.w;
  }
  __syncthreads();
  int pl = tid >> 2;
  int cq = (tid & 3) * 16;
  unsigned short* dst = xbf + ((size_t)(t * 2 + b) * HW + p0 + pl) * CCH + c0 + cq;
  bf16x8 o0, o1;
#pragma unroll
  for (int j = 0; j < 8; ++j) o0[j] = (short)f2bf(tile[cq + j][pl]);
#pragma unroll
  for (int j = 0; j < 8; ++j) o1[j] = (short)f2bf(tile[cq + 8 + j][pl]);
  *reinterpret_cast<bf16x8*>(dst) = o0;
  *reinterpret_cast<bf16x8*>(dst + 8) = o1;
}

// ---------------- GEMM: C[m][n] = sum_k A[m][k] * Bt[n][k] ----------------
// A: [M][384] bf16 row-major, Bt: [N][384] bf16 row-major.
// EPI=2: bf16 out pixel-major, column-routed: n<nsplit -> Cq (ldc 384,
//        *oscale), else -> Ckv (ldc 768). EPI=1: f32 d_out (+bias, tsel).
// 3-buffer LDS, depth-2 prefetch, counted vmcnt(4) + s_barrier per K-step.
// All grids must have (gridDim.x*gridDim.y) % 8 == 0 (XCD swizzle).
template <int EPI>
__global__ __launch_bounds__(256) void gemm_bt(
    const unsigned short* __restrict__ A,
    const unsigned short* __restrict__ Bt,
    unsigned short* __restrict__ Cq,
    unsigned short* __restrict__ Ckv,
    int nsplit,
    float* __restrict__ Cf,
    const float* __restrict__ bias,
    int tsel, float oscale) {
  // 3 buffers x (A: 4096 ushort | B: 4096 ushort) = 48 KB
  __shared__ __align__(16) unsigned short Lsh[3][8192];
  const int tid = threadIdx.x;
  const int lane = tid & 63;
  const int wid = tid >> 6, wr = wid >> 1, wc = wid & 1;

  // XCD-aware swizzle: consecutive logical ids share an operand panel.
  const int gx = gridDim.x;
  const int nwg = gx * gridDim.y;
  const int bid = blockIdx.x + blockIdx.y * gx;
  const int chunk = nwg >> 3;
  const int l = (bid & 7) * chunk + (bid >> 3);
  const int bx = l % gx, by = l / gx;

  const int m0 = (EPI == 1 ? bx : by) * 128;
  const int n0 = (EPI == 1 ? by : bx) * 128;
  const int r15 = lane & 15, g = lane >> 4;

  const int u1 = tid + 256;
  const unsigned short* srcA0 = A + (size_t)(m0 + (tid >> 2)) * 384 + (((tid & 3) ^ ((tid >> 3) & 3)) << 3);
  const unsigned short* srcA1 = A + (size_t)(m0 + (u1 >> 2)) * 384 + (((u1 & 3) ^ ((u1 >> 3) & 3)) << 3);
  const unsigned short* srcB0 = Bt + (size_t)(n0 + (tid >> 2)) * 384 + (((tid & 3) ^ ((tid >> 3) & 3)) << 3);
  const unsigned short* srcB1 = Bt + (size_t)(n0 + (u1 >> 2)) * 384 + (((u1 & 3) ^ ((u1 >> 3) & 3)) << 3);
  const int wbase = (tid & ~63) * 8;  // ushort units; wave-uniform

  f32x4 acc[4][4];
  f32x4 zero4 = {0.f, 0.f, 0.f, 0.f};
#pragma unroll
  for (int a = 0; a < 4; ++a)
#pragma unroll
    for (int b = 0; b < 4; ++b) acc[a][b] = zero4;

  const int swzr = (g ^ ((r15 >> 1) & 3)) << 3;  // ushort offset within 32-wide row

#define STAGE(buf, kt) do {                                  \
    int ke = (kt) * 32;                                      \
    gload16(srcA0 + ke, &Lsh[(buf)][wbase]);                 \
    gload16(srcA1 + ke, &Lsh[(buf)][2048 + wbase]);          \
    gload16(srcB0 + ke, &Lsh[(buf)][4096 + wbase]);          \
    gload16(srcB1 + ke, &Lsh[(buf)][6144 + wbase]);          \
  } while (0)

#define COMPUTE(buf) do {                                                       \
    bf16x8 af[4], bfv[4];                                                       \
    _Pragma("unroll")                                                           \
    for (int a = 0; a < 4; ++a)                                                 \
      af[a] = *(const bf16x8*)&Lsh[(buf)][(wr * 64 + a * 16 + r15) * 32 + swzr];\
    _Pragma("unroll")                                                           \
    for (int b = 0; b < 4; ++b)                                                 \
      bfv[b] = *(const bf16x8*)&Lsh[(buf)][4096 + (wc * 64 + b * 16 + r15) * 32 + swzr];\
    _Pragma("unroll")                                                           \
    for (int a = 0; a < 4; ++a)                                                 \
      _Pragma("unroll")                                                         \
      for (int b = 0; b < 4; ++b)                                               \
        acc[a][b] = __builtin_amdgcn_mfma_f32_16x16x32_bf16(af[a], bfv[b], acc[a][b], 0, 0, 0);\
  } while (0)

  STAGE(0, 0);
  STAGE(1, 1);
#pragma unroll
  for (int kt = 0; kt < 11; ++kt) {
    // own vmcnt(4) -> this wave's STAGE(kt) landed; barrier -> all waves'.
    // The 4 in flight are STAGE(kt+1): nobody reads that buffer this step.
    asm volatile("s_waitcnt vmcnt(4)" ::: "memory");
    __builtin_amdgcn_s_barrier();
    asm volatile("" ::: "memory");
    if (kt < 10) STAGE((kt + 2) % 3, kt + 2);
    COMPUTE(kt % 3);
  }
  __syncthreads();   // drains vmcnt(0): STAGE(11) complete for all waves
  COMPUTE(11 % 3);
#undef STAGE
#undef COMPUTE

  if (EPI == 2) {
    // pixel-major outputs: row index = m directly (m = b*HW + p)
    unsigned short* Cp;
    int ldc2, ncol0;
    float sc;
    if (n0 < nsplit) { Cp = Cq;  ldc2 = 384; ncol0 = n0;          sc = oscale; }
    else             { Cp = Ckv; ldc2 = 768; ncol0 = n0 - nsplit; sc = 1.0f;   }
#pragma unroll
    for (int a = 0; a < 4; ++a) {
      size_t rbase = (size_t)(m0 + wr * 64 + a * 16 + g * 4) * ldc2;
#pragma unroll
      for (int b = 0; b < 4; ++b) {
        int n = ncol0 + wc * 64 + b * 16 + r15;
        unsigned short* cp = Cp + rbase + n;
#pragma unroll
        for (int r = 0; r < 4; ++r) cp[(size_t)r * ldc2] = f2bf(acc[a][b][r] * sc);
      }
    }
  } else {
    int bb = n0 / HW;  // uniform per block
#pragma unroll
    for (int a = 0; a < 4; ++a) {
      int d = m0 + wr * 64 + a * 16 + g * 4;
#pragma unroll
      for (int b = 0; b < 4; ++b) {
        int n = n0 + wc * 64 + b * 16 + r15;
        int p = n - bb * HW;
#pragma unroll
        for (int r = 0; r < 4; ++r) {
          float v = acc[a][b][r] + bias[d + r];
          Cf[(((size_t)bb * CCH + (d + r)) * 2 + tsel) * HW + p] = v;
        }
      }
    }
  }
}

// ---------------- windowed attention ----------------
// q: [b][p][384] pixel-major (pre-scaled by hd^-0.5), kv: [b][p][768]
// (K=cols 0..383, V=cols 384..767), obuf: [b][p][384] pixel-major.
// Window row -> pixel mapping via per-block LDS table (built once).
// grid (256 windows, 2 batches), block 512 (8 waves = 8 heads).
__global__ __launch_bounds__(512, 2) void attn_kernel(
    const unsigned short* __restrict__ q,
    const unsigned short* __restrict__ kv,
    const int* __restrict__ mask,
    unsigned short* __restrict__ obuf) {
  __shared__ __align__(16) unsigned short P[8][16][168];
  __shared__ int ptab[144];
  const int n = blockIdx.x, b = blockIdx.y;
  const int tid = threadIdx.x;
  const int h = tid >> 6, lane = tid & 63;
  const int c15 = lane & 15, g = lane >> 4;
  const int wy = n >> 4, wx = n & 15;
  const size_t rowbase = (size_t)b * HW;
  const int* mrow = mask + (size_t)(b * 2 + 1) * HW;  // mask[b][t=1][0]

  if (tid < 144)
    ptab[tid] = (wy * 12 + tid / 12) * 192 + wx * 12 + tid % 12;

  // zero the P padding columns [144,168) once (own wave's region only)
  for (int idx = lane; idx < 16 * 24; idx += 64)
    P[h][idx / 24][144 + (idx % 24)] = 0;
  __syncthreads();

  float biasv[9];
#pragma unroll
  for (int nt = 0; nt < 9; ++nt)
    biasv[nt] = (mrow[ptab[nt * 16 + c15]] == 0) ? -1e9f : 0.0f;

  bf16x8 zfrag = {0, 0, 0, 0, 0, 0, 0, 0};
  f32x4 zero4 = {0.f, 0.f, 0.f, 0.f};

  // K fragments resident in registers for all 9 mt iterations.
  bf16x8 kf0[9], kf1[9];
#pragma unroll
  for (int nt = 0; nt < 9; ++nt) {
    const unsigned short* kp = kv + (rowbase + ptab[nt * 16 + c15]) * 768 + h * 48;
    kf0[nt] = *(const bf16x8*)(kp + g * 8);
    kf1[nt] = zfrag;
    if (g < 2) kf1[nt] = *(const bf16x8*)(kp + 32 + g * 8);
  }

  // V fragments (B operand of PV), resident in registers.
  const unsigned short* vb = kv + rowbase * 768 + 384 + h * 48;
  bf16x8 vf[5][3];
#pragma unroll
  for (int ks = 0; ks < 5; ++ks) {
#pragma unroll
    for (int dt = 0; dt < 3; ++dt) {
      bf16x8 v = {0, 0, 0, 0, 0, 0, 0, 0};
#pragma unroll
      for (int j = 0; j < 8; ++j) {
        int sk = ks * 32 + g * 8 + j;
        if (sk < 144)
          v[j] = (short)vb[(size_t)ptab[sk] * 768 + dt * 16 + c15];
      }
      vf[ks][dt] = v;
    }
  }

  // Q prefetch for mt=0
  bf16x8 qf0, qf1;
  {
    const unsigned short* qp = q + (rowbase + ptab[c15]) * 384 + h * 48;
    qf0 = *(const bf16x8*)(qp + g * 8);
    qf1 = zfrag;
    if (g < 2) qf1 = *(const bf16x8*)(qp + 32 + g * 8);
  }

  for (int mt = 0; mt < 9; ++mt) {
    bf16x8 qn0 = zfrag, qn1 = zfrag;
    if (mt < 8) {
      const unsigned short* qp = q + (rowbase + ptab[(mt + 1) * 16 + c15]) * 384 + h * 48;
      qn0 = *(const bf16x8*)(qp + g * 8);
      if (g < 2) qn1 = *(const bf16x8*)(qp + 32 + g * 8);
    }

    float l4[4] = {0.f, 0.f, 0.f, 0.f};
    f32x4 oacc[3];
#pragma unroll
    for (int dt = 0; dt < 3; ++dt) oacc[dt] = zero4;

#pragma unroll
    for (int nt = 0; nt < 9; ++nt) {
      f32x4 s = __builtin_amdgcn_mfma_f32_16x16x32_bf16(qf1, kf1[nt], zero4, 0, 0, 0);
      s = __builtin_amdgcn_mfma_f32_16x16x32_bf16(qf0, kf0[nt], s, 0, 0, 0);
#pragma unroll
      for (int r = 0; r < 4; ++r) {
        float pv = __expf(s[r] + biasv[nt]);
        l4[r] += pv;
        P[h][g * 4 + r][nt * 16 + c15] = f2bf(pv);
      }
      if (nt & 1) {
        int ks = nt >> 1;
        bf16x8 pf = *(const bf16x8*)&P[h][c15][ks * 32 + g * 8];
#pragma unroll
        for (int dt = 0; dt < 3; ++dt)
          oacc[dt] = __builtin_amdgcn_mfma_f32_16x16x32_bf16(pf, vf[ks][dt], oacc[dt], 0, 0, 0);
      }
    }
    // tail ks=4: cols 128..143 from nt=8, 144..159 are zero padding
    {
      bf16x8 pf = *(const bf16x8*)&P[h][c15][4 * 32 + g * 8];
#pragma unroll
      for (int dt = 0; dt < 3; ++dt)
        oacc[dt] = __builtin_amdgcn_mfma_f32_16x16x32_bf16(pf, vf[4][dt], oacc[dt], 0, 0, 0);
    }

#pragma unroll
    for (int s = 1; s < 16; s <<= 1)
#pragma unroll
      for (int r = 0; r < 4; ++r) l4[r] += __shfl_xor(l4[r], s, 64);

    float inv[4];
#pragma unroll
    for (int r = 0; r < 4; ++r) inv[r] = 1.0f / l4[r];
#pragma unroll
    for (int dt = 0; dt < 3; ++dt) {
#pragma unroll
      for (int r = 0; r < 4; ++r) {
        int so = mt * 16 + g * 4 + r;
        obuf[(rowbase + ptab[so]) * 384 + h * 48 + dt * 16 + c15] =
            f2bf(oacc[dt][r] * inv[r]);
      }
    }

    qf0 = qn0; qf1 = qn1;
  }
}

// ---------------- host ----------------
extern "C" void kernel_launch(void* const* d_in, const int* in_sizes, int n_in,
                              void* d_out, int out_size, void* d_ws, size_t ws_size,
                              hipStream_t stream) {
  const float* x    = (const float*)d_in[0];
  const int*   mask = (const int*)d_in[1];
  const float* wq1 = (const float*)d_in[2];
  const float* wk1 = (const float*)d_in[3];
  const float* wv1 = (const float*)d_in[4];
  const float* wo1 = (const float*)d_in[5];
  const float* wq2 = (const float*)d_in[6];
  const float* wk2 = (const float*)d_in[7];
  const float* wv2 = (const float*)d_in[8];
  const float* wo2 = (const float*)d_in[9];
  const float* pj1 = (const float*)d_in[10];
  const float* pj2 = (const float*)d_in[11];
  const float* bo1 = (const float*)d_in[12];
  const float* bo2 = (const float*)d_in[13];
  const float* pb1 = (const float*)d_in[14];
  const float* pb2 = (const float*)d_in[15];
  float* out = (float*)d_out;

  const float SCALE = 0.14433756729740643f;  // 48^-0.5, folded into Q

  char* ws = (char*)d_ws;
  size_t off = 0;
  unsigned short* wt   = (unsigned short*)(ws + off); off += (size_t)6 * W2 * 2;
  unsigned short* wfT  = (unsigned short*)(ws + off); off += (size_t)2 * W2 * 2;
  float*          bfu  = (float*)(ws + off);          off += (size_t)2 * 384 * 4;
  unsigned short* xbf  = (unsigned short*)(ws + off); off += (size_t)4 * HW * CCH * 2;
  size_t fixed = off;

  size_t qsz = (size_t)NPIX * 384 * 2, kvsz = (size_t)NPIX * 768 * 2, osz = qsz;
  bool fused = (ws_size >= fixed + 2 * qsz + 2 * kvsz + osz);
  if (!fused && ws_size < fixed + qsz + kvsz + osz) return;  // no room at all

  k_wt<<<dim3(576, 6), 256, 0, stream>>>(wq1, wk1, wv1, wq2, wk2, wv2, wt);
  k_wf<<<dim3(576, 2), 256, 0, stream>>>(wo1, pj1, wo2, pj2, wfT);
  k_bf<<<1, 768, 0, stream>>>(bo1, pj1, pb1, bo2, pj2, pb2, bfu);
  k_tx<<<dim3(576, 6, 4), 256, 0, stream>>>(x, xbf);

  if (fused) {
    unsigned short* qb[2] = {(unsigned short*)(ws + fixed),
                             (unsigned short*)(ws + fixed + qsz)};
    unsigned short* kvb[2] = {(unsigned short*)(ws + fixed + 2 * qsz),
                              (unsigned short*)(ws + fixed + 2 * qsz + kvsz)};
    unsigned short* obuf = (unsigned short*)(ws + fixed + 2 * qsz + 2 * kvsz);
    // frame f: A = xbf[frame f], weights = [wq_f | wk_{1-f} | wv_{1-f}]
    for (int f = 0; f < 2; ++f) {
      gemm_bt<2><<<dim3(9, 576), 256, 0, stream>>>(
          xbf + (size_t)f * 2 * HW * CCH, wt + (size_t)f * 3 * W2,
          qb[f], kvb[1 - f], 384, nullptr, nullptr, 0, SCALE);
    }
    for (int s = 0; s < 2; ++s) {
      attn_kernel<<<dim3(256, 2), 512, 0, stream>>>(qb[s], kvb[s], mask, obuf);
      gemm_bt<1><<<dim3(3, 576), 256, 0, stream>>>(
          wfT + (size_t)s * W2, obuf, nullptr, nullptr, 0, out, bfu + s * 384, s, 1.0f);
    }
  } else {
    unsigned short* qbuf = (unsigned short*)(ws + fixed);
    unsigned short* kvbuf = (unsigned short*)(ws + fixed + qsz);
    unsigned short* obuf = (unsigned short*)(ws + fixed + qsz + kvsz);
    for (int s = 0; s < 2; ++s) {
      const unsigned short* fq = xbf + (size_t)(s == 0 ? 0 : 1) * 2 * HW * CCH;
      const unsigned short* fk = xbf + (size_t)(s == 0 ? 1 : 0) * 2 * HW * CCH;
      gemm_bt<2><<<dim3(3, 576), 256, 0, stream>>>(
          fq, wt + (size_t)(s == 0 ? 0 : 3) * W2, qbuf, nullptr, 384,
          nullptr, nullptr, 0, SCALE);
      gemm_bt<2><<<dim3(6, 576), 256, 0, stream>>>(
          fk, wt + (size_t)(s == 0 ? 4 : 1) * W2, nullptr, kvbuf, 0,
          nullptr, nullptr, 0, 1.0f);
      attn_kernel<<<dim3(256, 2), 512, 0, stream>>>(qbuf, kvbuf, mask, obuf);
      gemm_bt<1><<<dim3(3, 576), 256, 0, stream>>>(
          wfT + (size_t)s * W2, obuf, nullptr, nullptr, 0, out, bfu + s * 384, s, 1.0f);
    }
  }
}

// Round 7
// 675.433 us; speedup vs baseline: 1.0067x; 1.0067x over previous
//
#include <hip/hip_runtime.h>
#include <stdint.h>

typedef __attribute__((ext_vector_type(8))) short bf16x8;
typedef __attribute__((ext_vector_type(4))) float f32x4;

#define HW    36864   // 192*192
#define CCH   384
#define NPIX  73728   // 2 batches * HW
#define W2    147456  // 384*384

__device__ __forceinline__ unsigned short f2bf(float f) {
  unsigned u = __builtin_bit_cast(unsigned, f);
  u += 0x7FFFu + ((u >> 16) & 1u);
  return (unsigned short)(u >> 16);
}

typedef const unsigned int __attribute__((address_space(1)))* gas1_t;
typedef unsigned int __attribute__((address_space(3)))* las3_t;
__device__ __forceinline__ void gload16(const void* g, void* l) {
  __builtin_amdgcn_global_load_lds((gas1_t)g, (las3_t)l, 16, 0, 0);
}

// ---------------- prep kernels ----------------

// wt slots: 0=wq1, 1=wk2, 2=wv2, 3=wq2, 4=wk1, 5=wv1  (frame-fused order)
__global__ void k_wt(const float* __restrict__ w0, const float* __restrict__ w1,
                     const float* __restrict__ w2, const float* __restrict__ w3,
                     const float* __restrict__ w4, const float* __restrict__ w5,
                     unsigned short* __restrict__ wt) {
  int idx = blockIdx.x * 256 + threadIdx.x;   // 0..147455
  int w = blockIdx.y;                          // input index: q1,k1,v1,q2,k2,v2
  const float* W;
  switch (w) { case 0: W = w0; break; case 1: W = w1; break;
               case 2: W = w2; break; case 3: W = w3; break;
               case 4: W = w4; break; default: W = w5; break; }
  const int slotmap[6] = {0, 4, 5, 3, 1, 2};
  int slot = slotmap[w];
  int c = idx / 384, d = idx % 384;
  wt[(size_t)slot * W2 + (size_t)d * 384 + c] = f2bf(W[(size_t)c * 384 + d]);
}

__global__ void k_wf(const float* __restrict__ wo1, const float* __restrict__ pj1,
                     const float* __restrict__ wo2, const float* __restrict__ pj2,
                     unsigned short* __restrict__ wfT) {
  int idx = blockIdx.x * 256 + threadIdx.x;
  int s = blockIdx.y;
  const float* wo = s ? wo2 : wo1;
  const float* pj = s ? pj2 : pj1;
  int d = idx / 384, e = idx % 384;
  float acc = 0.f;
  for (int c = 0; c < 384; ++c) acc += pj[d * 384 + c] * wo[e * 384 + c];
  wfT[(size_t)s * W2 + (size_t)d * 384 + e] = f2bf(acc);
}

__global__ void k_bf(const float* __restrict__ bo1, const float* __restrict__ pj1,
                     const float* __restrict__ pb1, const float* __restrict__ bo2,
                     const float* __restrict__ pj2, const float* __restrict__ pb2,
                     float* __restrict__ bfused) {
  int t = threadIdx.x;  // 0..767
  int s = t / 384, d = t % 384;
  const float* bo = s ? bo2 : bo1;
  const float* pj = s ? pj2 : pj1;
  const float* pb = s ? pb2 : pb1;
  float acc = pb[d];
  for (int c = 0; c < 384; ++c) acc += pj[d * 384 + c] * bo[c];
  bfused[t] = acc;
}

// xbf[t][b][p][c] = bf16( x[b][c][t][p] )
__global__ __launch_bounds__(256) void k_tx(const float* __restrict__ x,
                                            unsigned short* __restrict__ xbf) {
  __shared__ float tile[64][65];
  int p0 = blockIdx.x * 64;
  int c0 = blockIdx.y * 64;
  int bt = blockIdx.z;  // b*2 + t
  int b = bt >> 1, t = bt & 1;
  int tid = threadIdx.x;
  int cl = tid >> 2;
  int pq = (tid & 3) * 4;
  const float* src = x + (((size_t)b * CCH + (c0 + cl)) * 2 + t) * HW + p0;
#pragma unroll
  for (int i = 0; i < 4; ++i) {
    int p_l = pq + i * 16;
    float4 v = *reinterpret_cast<const float4*>(src + p_l);
    tile[cl][p_l + 0] = v.x; tile[cl][p_l + 1] = v.y;
    tile[cl][p_l + 2] = v.z; tile[cl][p_l + 3] = v.w;
  }
  __syncthreads();
  int pl = tid >> 2;
  int cq = (tid & 3) * 16;
  unsigned short* dst = xbf + ((size_t)(t * 2 + b) * HW + p0 + pl) * CCH + c0 + cq;
  bf16x8 o0, o1;
#pragma unroll
  for (int j = 0; j < 8; ++j) o0[j] = (short)f2bf(tile[cq + j][pl]);
#pragma unroll
  for (int j = 0; j < 8; ++j) o1[j] = (short)f2bf(tile[cq + 8 + j][pl]);
  *reinterpret_cast<bf16x8*>(dst) = o0;
  *reinterpret_cast<bf16x8*>(dst + 8) = o1;
}

// ---------------- GEMM: C[m][n] = sum_k A[m][k] * Bt[n][k] ----------------
// A: [M][384] bf16 row-major, Bt: [N][384] bf16 row-major.
// EPI=2: bf16 out pixel-major, column-routed: n<nsplit -> Cq (ldc 384,
//        *oscale), else -> Ckv (ldc 768). EPI=1: f32 d_out (+bias, tsel).
// 3-buffer LDS, depth-2 prefetch, counted vmcnt(4) + s_barrier per K-step.
// All grids must have (gridDim.x*gridDim.y) % 8 == 0 (XCD swizzle).
template <int EPI>
__global__ __launch_bounds__(256) void gemm_bt(
    const unsigned short* __restrict__ A,
    const unsigned short* __restrict__ Bt,
    unsigned short* __restrict__ Cq,
    unsigned short* __restrict__ Ckv,
    int nsplit,
    float* __restrict__ Cf,
    const float* __restrict__ bias,
    int tsel, float oscale) {
  // 3 buffers x (A: 4096 ushort | B: 4096 ushort) = 48 KB
  __shared__ __align__(16) unsigned short Lsh[3][8192];
  const int tid = threadIdx.x;
  const int lane = tid & 63;
  const int wid = tid >> 6, wr = wid >> 1, wc = wid & 1;

  // XCD-aware swizzle: consecutive logical ids share an operand panel.
  const int gx = gridDim.x;
  const int nwg = gx * gridDim.y;
  const int bid = blockIdx.x + blockIdx.y * gx;
  const int chunk = nwg >> 3;
  const int l = (bid & 7) * chunk + (bid >> 3);
  const int bx = l % gx, by = l / gx;

  const int m0 = (EPI == 1 ? bx : by) * 128;
  const int n0 = (EPI == 1 ? by : bx) * 128;
  const int r15 = lane & 15, g = lane >> 4;

  const int u1 = tid + 256;
  const unsigned short* srcA0 = A + (size_t)(m0 + (tid >> 2)) * 384 + (((tid & 3) ^ ((tid >> 3) & 3)) << 3);
  const unsigned short* srcA1 = A + (size_t)(m0 + (u1 >> 2)) * 384 + (((u1 & 3) ^ ((u1 >> 3) & 3)) << 3);
  const unsigned short* srcB0 = Bt + (size_t)(n0 + (tid >> 2)) * 384 + (((tid & 3) ^ ((tid >> 3) & 3)) << 3);
  const unsigned short* srcB1 = Bt + (size_t)(n0 + (u1 >> 2)) * 384 + (((u1 & 3) ^ ((u1 >> 3) & 3)) << 3);
  const int wbase = (tid & ~63) * 8;  // ushort units; wave-uniform

  f32x4 acc[4][4];
  f32x4 zero4 = {0.f, 0.f, 0.f, 0.f};
#pragma unroll
  for (int a = 0; a < 4; ++a)
#pragma unroll
    for (int b = 0; b < 4; ++b) acc[a][b] = zero4;

  const int swzr = (g ^ ((r15 >> 1) & 3)) << 3;  // ushort offset within 32-wide row

#define STAGE(buf, kt) do {                                  \
    int ke = (kt) * 32;                                      \
    gload16(srcA0 + ke, &Lsh[(buf)][wbase]);                 \
    gload16(srcA1 + ke, &Lsh[(buf)][2048 + wbase]);          \
    gload16(srcB0 + ke, &Lsh[(buf)][4096 + wbase]);          \
    gload16(srcB1 + ke, &Lsh[(buf)][6144 + wbase]);          \
  } while (0)

#define COMPUTE(buf) do {                                                       \
    bf16x8 af[4], bfv[4];                                                       \
    _Pragma("unroll")                                                           \
    for (int a = 0; a < 4; ++a)                                                 \
      af[a] = *(const bf16x8*)&Lsh[(buf)][(wr * 64 + a * 16 + r15) * 32 + swzr];\
    _Pragma("unroll")                                                           \
    for (int b = 0; b < 4; ++b)                                                 \
      bfv[b] = *(const bf16x8*)&Lsh[(buf)][4096 + (wc * 64 + b * 16 + r15) * 32 + swzr];\
    _Pragma("unroll")                                                           \
    for (int a = 0; a < 4; ++a)                                                 \
      _Pragma("unroll")                                                         \
      for (int b = 0; b < 4; ++b)                                               \
        acc[a][b] = __builtin_amdgcn_mfma_f32_16x16x32_bf16(af[a], bfv[b], acc[a][b], 0, 0, 0);\
  } while (0)

  STAGE(0, 0);
  STAGE(1, 1);
#pragma unroll
  for (int kt = 0; kt < 11; ++kt) {
    // own vmcnt(4) -> this wave's STAGE(kt) landed; barrier -> all waves'.
    // The 4 in flight are STAGE(kt+1): nobody reads that buffer this step.
    asm volatile("s_waitcnt vmcnt(4)" ::: "memory");
    __builtin_amdgcn_s_barrier();
    asm volatile("" ::: "memory");
    if (kt < 10) STAGE((kt + 2) % 3, kt + 2);
    COMPUTE(kt % 3);
  }
  __syncthreads();   // drains vmcnt(0): STAGE(11) complete for all waves
  COMPUTE(11 % 3);
#undef STAGE
#undef COMPUTE

  if (EPI == 2) {
    // pixel-major outputs: row index = m directly (m = b*HW + p)
    unsigned short* Cp;
    int ldc2, ncol0;
    float sc;
    if (n0 < nsplit) { Cp = Cq;  ldc2 = 384; ncol0 = n0;          sc = oscale; }
    else             { Cp = Ckv; ldc2 = 768; ncol0 = n0 - nsplit; sc = 1.0f;   }
#pragma unroll
    for (int a = 0; a < 4; ++a) {
      size_t rbase = (size_t)(m0 + wr * 64 + a * 16 + g * 4) * ldc2;
#pragma unroll
      for (int b = 0; b < 4; ++b) {
        int n = ncol0 + wc * 64 + b * 16 + r15;
        unsigned short* cp = Cp + rbase + n;
#pragma unroll
        for (int r = 0; r < 4; ++r) cp[(size_t)r * ldc2] = f2bf(acc[a][b][r] * sc);
      }
    }
  } else {
    int bb = n0 / HW;  // uniform per block
#pragma unroll
    for (int a = 0; a < 4; ++a) {
      int d = m0 + wr * 64 + a * 16 + g * 4;
#pragma unroll
      for (int b = 0; b < 4; ++b) {
        int n = n0 + wc * 64 + b * 16 + r15;
        int p = n - bb * HW;
#pragma unroll
        for (int r = 0; r < 4; ++r) {
          float v = acc[a][b][r] + bias[d + r];
          Cf[(((size_t)bb * CCH + (d + r)) * 2 + tsel) * HW + p] = v;
        }
      }
    }
  }
}

// ---------------- windowed attention ----------------
// q: [b][p][384] pixel-major (pre-scaled by hd^-0.5), kv: [b][p][768]
// (K=cols 0..383, V=cols 384..767), obuf: [b][p][384] pixel-major.
// Window row -> pixel mapping via per-block LDS table (built once).
// grid (256 windows, 2 batches), block 512 (8 waves = 8 heads).
__global__ __launch_bounds__(512, 2) void attn_kernel(
    const unsigned short* __restrict__ q,
    const unsigned short* __restrict__ kv,
    const int* __restrict__ mask,
    unsigned short* __restrict__ obuf) {
  __shared__ __align__(16) unsigned short P[8][16][168];
  __shared__ int ptab[144];
  const int n = blockIdx.x, b = blockIdx.y;
  const int tid = threadIdx.x;
  const int h = tid >> 6, lane = tid & 63;
  const int c15 = lane & 15, g = lane >> 4;
  const int wy = n >> 4, wx = n & 15;
  const size_t rowbase = (size_t)b * HW;
  const int* mrow = mask + (size_t)(b * 2 + 1) * HW;  // mask[b][t=1][0]

  if (tid < 144)
    ptab[tid] = (wy * 12 + tid / 12) * 192 + wx * 12 + tid % 12;

  // zero the P padding columns [144,168) once (own wave's region only)
  for (int idx = lane; idx < 16 * 24; idx += 64)
    P[h][idx / 24][144 + (idx % 24)] = 0;
  __syncthreads();

  float biasv[9];
#pragma unroll
  for (int nt = 0; nt < 9; ++nt)
    biasv[nt] = (mrow[ptab[nt * 16 + c15]] == 0) ? -1e9f : 0.0f;

  bf16x8 zfrag = {0, 0, 0, 0, 0, 0, 0, 0};
  f32x4 zero4 = {0.f, 0.f, 0.f, 0.f};

  // K fragments resident in registers for all 9 mt iterations.
  bf16x8 kf0[9], kf1[9];
#pragma unroll
  for (int nt = 0; nt < 9; ++nt) {
    const unsigned short* kp = kv + (rowbase + ptab[nt * 16 + c15]) * 768 + h * 48;
    kf0[nt] = *(const bf16x8*)(kp + g * 8);
    kf1[nt] = zfrag;
    if (g < 2) kf1[nt] = *(const bf16x8*)(kp + 32 + g * 8);
  }

  // V fragments (B operand of PV), resident in registers.
  const unsigned short* vb = kv + rowbase * 768 + 384 + h * 48;
  bf16x8 vf[5][3];
#pragma unroll
  for (int ks = 0; ks < 5; ++ks) {
#pragma unroll
    for (int dt = 0; dt < 3; ++dt) {
      bf16x8 v = {0, 0, 0, 0, 0, 0, 0, 0};
#pragma unroll
      for (int j = 0; j < 8; ++j) {
        int sk = ks * 32 + g * 8 + j;
        if (sk < 144)
          v[j] = (short)vb[(size_t)ptab[sk] * 768 + dt * 16 + c15];
      }
      vf[ks][dt] = v;
    }
  }

  // Q prefetch for mt=0
  bf16x8 qf0, qf1;
  {
    const unsigned short* qp = q + (rowbase + ptab[c15]) * 384 + h * 48;
    qf0 = *(const bf16x8*)(qp + g * 8);
    qf1 = zfrag;
    if (g < 2) qf1 = *(const bf16x8*)(qp + 32 + g * 8);
  }

  for (int mt = 0; mt < 9; ++mt) {
    bf16x8 qn0 = zfrag, qn1 = zfrag;
    if (mt < 8) {
      const unsigned short* qp = q + (rowbase + ptab[(mt + 1) * 16 + c15]) * 384 + h * 48;
      qn0 = *(const bf16x8*)(qp + g * 8);
      if (g < 2) qn1 = *(const bf16x8*)(qp + 32 + g * 8);
    }

    float l4[4] = {0.f, 0.f, 0.f, 0.f};
    f32x4 oacc[3];
#pragma unroll
    for (int dt = 0; dt < 3; ++dt) oacc[dt] = zero4;

#pragma unroll
    for (int nt = 0; nt < 9; ++nt) {
      f32x4 s = __builtin_amdgcn_mfma_f32_16x16x32_bf16(qf1, kf1[nt], zero4, 0, 0, 0);
      s = __builtin_amdgcn_mfma_f32_16x16x32_bf16(qf0, kf0[nt], s, 0, 0, 0);
#pragma unroll
      for (int r = 0; r < 4; ++r) {
        float pv = __expf(s[r] + biasv[nt]);
        l4[r] += pv;
        P[h][g * 4 + r][nt * 16 + c15] = f2bf(pv);
      }
      if (nt & 1) {
        int ks = nt >> 1;
        bf16x8 pf = *(const bf16x8*)&P[h][c15][ks * 32 + g * 8];
#pragma unroll
        for (int dt = 0; dt < 3; ++dt)
          oacc[dt] = __builtin_amdgcn_mfma_f32_16x16x32_bf16(pf, vf[ks][dt], oacc[dt], 0, 0, 0);
      }
    }
    // tail ks=4: cols 128..143 from nt=8, 144..159 are zero padding
    {
      bf16x8 pf = *(const bf16x8*)&P[h][c15][4 * 32 + g * 8];
#pragma unroll
      for (int dt = 0; dt < 3; ++dt)
        oacc[dt] = __builtin_amdgcn_mfma_f32_16x16x32_bf16(pf, vf[4][dt], oacc[dt], 0, 0, 0);
    }

#pragma unroll
    for (int s = 1; s < 16; s <<= 1)
#pragma unroll
      for (int r = 0; r < 4; ++r) l4[r] += __shfl_xor(l4[r], s, 64);

    float inv[4];
#pragma unroll
    for (int r = 0; r < 4; ++r) inv[r] = 1.0f / l4[r];
#pragma unroll
    for (int dt = 0; dt < 3; ++dt) {
#pragma unroll
      for (int r = 0; r < 4; ++r) {
        int so = mt * 16 + g * 4 + r;
        obuf[(rowbase + ptab[so]) * 384 + h * 48 + dt * 16 + c15] =
            f2bf(oacc[dt][r] * inv[r]);
      }
    }

    qf0 = qn0; qf1 = qn1;
  }
}

// ---------------- host ----------------
extern "C" void kernel_launch(void* const* d_in, const int* in_sizes, int n_in,
                              void* d_out, int out_size, void* d_ws, size_t ws_size,
                              hipStream_t stream) {
  const float* x    = (const float*)d_in[0];
  const int*   mask = (const int*)d_in[1];
  const float* wq1 = (const float*)d_in[2];
  const float* wk1 = (const float*)d_in[3];
  const float* wv1 = (const float*)d_in[4];
  const float* wo1 = (const float*)d_in[5];
  const float* wq2 = (const float*)d_in[6];
  const float* wk2 = (const float*)d_in[7];
  const float* wv2 = (const float*)d_in[8];
  const float* wo2 = (const float*)d_in[9];
  const float* pj1 = (const float*)d_in[10];
  const float* pj2 = (const float*)d_in[11];
  const float* bo1 = (const float*)d_in[12];
  const float* bo2 = (const float*)d_in[13];
  const float* pb1 = (const float*)d_in[14];
  const float* pb2 = (const float*)d_in[15];
  float* out = (float*)d_out;

  const float SCALE = 0.14433756729740643f;  // 48^-0.5, folded into Q

  char* ws = (char*)d_ws;
  size_t off = 0;
  unsigned short* wt   = (unsigned short*)(ws + off); off += (size_t)6 * W2 * 2;
  unsigned short* wfT  = (unsigned short*)(ws + off); off += (size_t)2 * W2 * 2;
  float*          bfu  = (float*)(ws + off);          off += (size_t)2 * 384 * 4;
  unsigned short* xbf  = (unsigned short*)(ws + off); off += (size_t)4 * HW * CCH * 2;
  size_t fixed = off;

  size_t qsz = (size_t)NPIX * 384 * 2, kvsz = (size_t)NPIX * 768 * 2, osz = qsz;
  bool fused = (ws_size >= fixed + 2 * qsz + 2 * kvsz + osz);
  if (!fused && ws_size < fixed + qsz + kvsz + osz) return;  // no room at all

  k_wt<<<dim3(576, 6), 256, 0, stream>>>(wq1, wk1, wv1, wq2, wk2, wv2, wt);
  k_wf<<<dim3(576, 2), 256, 0, stream>>>(wo1, pj1, wo2, pj2, wfT);
  k_bf<<<1, 768, 0, stream>>>(bo1, pj1, pb1, bo2, pj2, pb2, bfu);
  k_tx<<<dim3(576, 6, 4), 256, 0, stream>>>(x, xbf);

  if (fused) {
    unsigned short* qb[2] = {(unsigned short*)(ws + fixed),
                             (unsigned short*)(ws + fixed + qsz)};
    unsigned short* kvb[2] = {(unsigned short*)(ws + fixed + 2 * qsz),
                              (unsigned short*)(ws + fixed + 2 * qsz + kvsz)};
    unsigned short* obuf = (unsigned short*)(ws + fixed + 2 * qsz + 2 * kvsz);
    // frame f: A = xbf[frame f], weights = [wq_f | wk_{1-f} | wv_{1-f}]
    for (int f = 0; f < 2; ++f) {
      gemm_bt<2><<<dim3(9, 576), 256, 0, stream>>>(
          xbf + (size_t)f * 2 * HW * CCH, wt + (size_t)f * 3 * W2,
          qb[f], kvb[1 - f], 384, nullptr, nullptr, 0, SCALE);
    }
    for (int s = 0; s < 2; ++s) {
      attn_kernel<<<dim3(256, 2), 512, 0, stream>>>(qb[s], kvb[s], mask, obuf);
      gemm_bt<1><<<dim3(3, 576), 256, 0, stream>>>(
          wfT + (size_t)s * W2, obuf, nullptr, nullptr, 0, out, bfu + s * 384, s, 1.0f);
    }
  } else {
    unsigned short* qbuf = (unsigned short*)(ws + fixed);
    unsigned short* kvbuf = (unsigned short*)(ws + fixed + qsz);
    unsigned short* obuf = (unsigned short*)(ws + fixed + qsz + kvsz);
    for (int s = 0; s < 2; ++s) {
      const unsigned short* fq = xbf + (size_t)(s == 0 ? 0 : 1) * 2 * HW * CCH;
      const unsigned short* fk = xbf + (size_t)(s == 0 ? 1 : 0) * 2 * HW * CCH;
      gemm_bt<2><<<dim3(3, 576), 256, 0, stream>>>(
          fq, wt + (size_t)(s == 0 ? 0 : 3) * W2, qbuf, nullptr, 384,
          nullptr, nullptr, 0, SCALE);
      gemm_bt<2><<<dim3(6, 576), 256, 0, stream>>>(
          fk, wt + (size_t)(s == 0 ? 4 : 1) * W2, nullptr, kvbuf, 0,
          nullptr, nullptr, 0, 1.0f);
      attn_kernel<<<dim3(256, 2), 512, 0, stream>>>(qbuf, kvbuf, mask, obuf);
      gemm_bt<1><<<dim3(3, 576), 256, 0, stream>>>(
          wfT + (size_t)s * W2, obuf, nullptr, nullptr, 0, out, bfu + s * 384, s, 1.0f);
    }
  }
}